// Round 1
// baseline (3302.209 us; speedup 1.0000x reference)
//
#include <hip/hip_runtime.h>

#define N_NODES 100000
#define E_EDGES 3200000
#define F_IN    512
#define C_OUT   64

// ---------------------------------------------------------------------------
// zero: clear the agg accumulator (d_out, poisoned 0xAA) and degree arrays
// ---------------------------------------------------------------------------
__global__ __launch_bounds__(256) void zero_kernel(float* __restrict__ out,
                                                   int* __restrict__ deg_out,
                                                   int* __restrict__ deg_in) {
    int idx = blockIdx.x * 256 + threadIdx.x;
    if (idx < N_NODES * C_OUT) out[idx] = 0.0f;
    if (idx < N_NODES) { deg_out[idx] = 0; deg_in[idx] = 0; }
}

// ---------------------------------------------------------------------------
// degrees: histogram src -> deg_out, dst -> deg_in
// ---------------------------------------------------------------------------
__global__ __launch_bounds__(256) void degree_kernel(const int* __restrict__ src,
                                                     const int* __restrict__ dst,
                                                     int* __restrict__ deg_out,
                                                     int* __restrict__ deg_in) {
    int e = blockIdx.x * 256 + threadIdx.x;
    if (e < E_EDGES) {
        atomicAdd(&deg_out[src[e]], 1);
        atomicAdd(&deg_in[dst[e]], 1);
    }
}

// ---------------------------------------------------------------------------
// GEMM: h0[n][c] = sum_f A[n][f] * W[c][f] + bias[c]
// BM=64 rows, BN=64 cols (= all of C), BK=32. 256 threads, 4x4 microtile.
// ---------------------------------------------------------------------------
__global__ __launch_bounds__(256) void gemm_kernel(const float* __restrict__ A,
                                                   const float* __restrict__ W,
                                                   const float* __restrict__ bias,
                                                   float* __restrict__ h0) {
    __shared__ float As[32][64];   // [k][m]
    __shared__ float Bs[32][64];   // [k][c]  (Bs[k][c] = W[c][k0+k])

    const int tid = threadIdx.x;
    const int tx = tid & 15;       // col group 0..15
    const int ty = tid >> 4;       // row group 0..15
    const int row0 = blockIdx.x * 64;

    float acc[4][4] = {};

    for (int k0 = 0; k0 < F_IN; k0 += 32) {
        // --- load A tile: 64 rows x 32 k, float4 per thread x2 halves ---
        {
            int r  = tid >> 3;            // 0..31
            int c4 = (tid & 7) * 4;       // 0..28
            #pragma unroll
            for (int half = 0; half < 2; ++half) {
                int rr = r + half * 32;
                int grow = row0 + rr;
                float4 v = make_float4(0.f, 0.f, 0.f, 0.f);
                if (grow < N_NODES)
                    v = *reinterpret_cast<const float4*>(&A[(size_t)grow * F_IN + k0 + c4]);
                As[c4 + 0][rr] = v.x;
                As[c4 + 1][rr] = v.y;
                As[c4 + 2][rr] = v.z;
                As[c4 + 3][rr] = v.w;
            }
        }
        // --- load B tile: Bs[k][c] = W[c][k0+k], 8 floats per thread ---
        {
            int c   = tid >> 2;           // 0..63
            int kk8 = (tid & 3) * 8;      // 0,8,16,24
            float4 v0 = *reinterpret_cast<const float4*>(&W[(size_t)c * F_IN + k0 + kk8]);
            float4 v1 = *reinterpret_cast<const float4*>(&W[(size_t)c * F_IN + k0 + kk8 + 4]);
            Bs[kk8 + 0][c] = v0.x;
            Bs[kk8 + 1][c] = v0.y;
            Bs[kk8 + 2][c] = v0.z;
            Bs[kk8 + 3][c] = v0.w;
            Bs[kk8 + 4][c] = v1.x;
            Bs[kk8 + 5][c] = v1.y;
            Bs[kk8 + 6][c] = v1.z;
            Bs[kk8 + 7][c] = v1.w;
        }
        __syncthreads();

        #pragma unroll
        for (int kk = 0; kk < 32; ++kk) {
            float4 a = *reinterpret_cast<const float4*>(&As[kk][ty * 4]);
            float4 b = *reinterpret_cast<const float4*>(&Bs[kk][tx * 4]);
            acc[0][0] += a.x * b.x; acc[0][1] += a.x * b.y; acc[0][2] += a.x * b.z; acc[0][3] += a.x * b.w;
            acc[1][0] += a.y * b.x; acc[1][1] += a.y * b.y; acc[1][2] += a.y * b.z; acc[1][3] += a.y * b.w;
            acc[2][0] += a.z * b.x; acc[2][1] += a.z * b.y; acc[2][2] += a.z * b.z; acc[2][3] += a.z * b.w;
            acc[3][0] += a.w * b.x; acc[3][1] += a.w * b.y; acc[3][2] += a.w * b.z; acc[3][3] += a.w * b.w;
        }
        __syncthreads();
    }

    // --- epilogue: add bias, store h0 ---
    float bx = bias[tx * 4 + 0];
    float by = bias[tx * 4 + 1];
    float bz = bias[tx * 4 + 2];
    float bw = bias[tx * 4 + 3];
    #pragma unroll
    for (int i = 0; i < 4; ++i) {
        int grow = row0 + ty * 4 + i;
        if (grow < N_NODES) {
            float4 o;
            o.x = acc[i][0] + bx;
            o.y = acc[i][1] + by;
            o.z = acc[i][2] + bz;
            o.w = acc[i][3] + bw;
            *reinterpret_cast<float4*>(&h0[(size_t)grow * C_OUT + tx * 4]) = o;
        }
    }
}

// ---------------------------------------------------------------------------
// scatter: for each edge e, out[dst[e]][c] += h0[src[e]][c] * rsqrt(deg_out[src])
// 16 threads per edge (4 channels each, float4 gather).
// ---------------------------------------------------------------------------
__global__ __launch_bounds__(256) void scatter_kernel(const int* __restrict__ src,
                                                      const int* __restrict__ dst,
                                                      const float* __restrict__ h0,
                                                      const int* __restrict__ deg_out,
                                                      float* __restrict__ out) {
    int idx = blockIdx.x * 256 + threadIdx.x;   // E*16 = 51.2M < 2^31
    int e  = idx >> 4;
    int c4 = (idx & 15) * 4;
    if (e < E_EDGES) {
        int s = src[e];
        int d = dst[e];
        int dg = deg_out[s];
        float ns = rsqrtf((float)(dg < 1 ? 1 : dg));
        float4 v = *reinterpret_cast<const float4*>(&h0[(size_t)s * C_OUT + c4]);
        float* o = &out[(size_t)d * C_OUT + c4];
        atomicAdd(o + 0, v.x * ns);
        atomicAdd(o + 1, v.y * ns);
        atomicAdd(o + 2, v.z * ns);
        atomicAdd(o + 3, v.w * ns);
    }
}

// ---------------------------------------------------------------------------
// final: out = (1-alpha) * rsqrt(deg_in) * agg + alpha * h0   (agg lives in out)
// ---------------------------------------------------------------------------
__global__ __launch_bounds__(256) void final_kernel(const float* __restrict__ h0,
                                                    const int* __restrict__ deg_in,
                                                    float* __restrict__ out) {
    int idx = blockIdx.x * 256 + threadIdx.x;   // N*16
    if (idx < N_NODES * 16) {
        int n  = idx >> 4;
        int c4 = (idx & 15) * 4;
        int dg = deg_in[n];
        float nd = rsqrtf((float)(dg < 1 ? 1 : dg));
        size_t off = (size_t)n * C_OUT + c4;
        float4 a = *reinterpret_cast<const float4*>(&out[off]);
        float4 h = *reinterpret_cast<const float4*>(&h0[off]);
        float4 r;
        r.x = 0.8f * nd * a.x + 0.2f * h.x;
        r.y = 0.8f * nd * a.y + 0.2f * h.y;
        r.z = 0.8f * nd * a.z + 0.2f * h.z;
        r.w = 0.8f * nd * a.w + 0.2f * h.w;
        *reinterpret_cast<float4*>(&out[off]) = r;
    }
}

// ---------------------------------------------------------------------------
extern "C" void kernel_launch(void* const* d_in, const int* in_sizes, int n_in,
                              void* d_out, int out_size, void* d_ws, size_t ws_size,
                              hipStream_t stream) {
    const float* in_feat = (const float*)d_in[0];   // [N, 512]
    const float* W       = (const float*)d_in[1];   // [64, 512]
    const float* bias    = (const float*)d_in[2];   // [64]
    const int*   src     = (const int*)d_in[3];     // [E] (int32: jax x64 off)
    const int*   dst     = (const int*)d_in[4];     // [E]
    float* out = (float*)d_out;                     // [N, 64] — doubles as agg

    // workspace layout: h0 (N*C floats) | deg_out (N ints) | deg_in (N ints)
    float* h0      = (float*)d_ws;
    int*   deg_out = (int*)(h0 + (size_t)N_NODES * C_OUT);
    int*   deg_in  = deg_out + N_NODES;

    zero_kernel<<<(N_NODES * C_OUT + 255) / 256, 256, 0, stream>>>(out, deg_out, deg_in);
    degree_kernel<<<(E_EDGES + 255) / 256, 256, 0, stream>>>(src, dst, deg_out, deg_in);
    gemm_kernel<<<(N_NODES + 63) / 64, 256, 0, stream>>>(in_feat, W, bias, h0);
    scatter_kernel<<<(E_EDGES * 16) / 256, 256, 0, stream>>>(src, dst, h0, deg_out, out);
    final_kernel<<<(N_NODES * 16 + 255) / 256, 256, 0, stream>>>(h0, deg_in, out);
}

// Round 2
// 1030.222 us; speedup vs baseline: 3.2053x; 3.2053x over previous
//
#include <hip/hip_runtime.h>

#define N_NODES 100000
#define E_EDGES 3200000
#define F_IN    512
#define C_OUT   64
#define NBLK    391   // ceil(N_NODES / 256)

// ---------------------------------------------------------------------------
// zero: clear degree arrays (ws is poisoned 0xAA before every call)
// ---------------------------------------------------------------------------
__global__ __launch_bounds__(256) void zero_kernel(int* __restrict__ deg_out,
                                                   int* __restrict__ deg_in) {
    int idx = blockIdx.x * 256 + threadIdx.x;
    if (idx < N_NODES) { deg_out[idx] = 0; deg_in[idx] = 0; }
}

// ---------------------------------------------------------------------------
// degrees: histogram src -> deg_out, dst -> deg_in (int atomics, cheap)
// ---------------------------------------------------------------------------
__global__ __launch_bounds__(256) void degree_kernel(const int* __restrict__ src,
                                                     const int* __restrict__ dst,
                                                     int* __restrict__ deg_out,
                                                     int* __restrict__ deg_in) {
    int e = blockIdx.x * 256 + threadIdx.x;
    if (e < E_EDGES) {
        atomicAdd(&deg_out[src[e]], 1);
        atomicAdd(&deg_in[dst[e]], 1);
    }
}

// ---------------------------------------------------------------------------
// scan stage 1: per-block exclusive scan of deg_in, emit block totals
// ---------------------------------------------------------------------------
__global__ __launch_bounds__(256) void scan_block(const int* __restrict__ deg,
                                                  int* __restrict__ excl,
                                                  int* __restrict__ blk_sums) {
    __shared__ int s[256];
    int t = threadIdx.x;
    int idx = blockIdx.x * 256 + t;
    int v = (idx < N_NODES) ? deg[idx] : 0;
    s[t] = v;
    __syncthreads();
    #pragma unroll
    for (int off = 1; off < 256; off <<= 1) {
        int add = (t >= off) ? s[t - off] : 0;
        __syncthreads();
        s[t] += add;
        __syncthreads();
    }
    if (idx < N_NODES) excl[idx] = s[t] - v;       // exclusive within block
    if (t == 255) blk_sums[blockIdx.x] = s[255];   // block total
}

// ---------------------------------------------------------------------------
// scan stage 2: exclusive scan of the 391 block totals (single block)
// ---------------------------------------------------------------------------
__global__ __launch_bounds__(512) void scan_tops(int* __restrict__ blk_sums) {
    __shared__ int s[512];
    int t = threadIdx.x;
    int v = (t < NBLK) ? blk_sums[t] : 0;
    s[t] = v;
    __syncthreads();
    #pragma unroll
    for (int off = 1; off < 512; off <<= 1) {
        int add = (t >= off) ? s[t - off] : 0;
        __syncthreads();
        s[t] += add;
        __syncthreads();
    }
    if (t < NBLK) blk_sums[t] = s[t] - v;          // exclusive
}

// ---------------------------------------------------------------------------
// scan stage 3: add block offsets -> global row_off; init cursor; norms
// ---------------------------------------------------------------------------
__global__ __launch_bounds__(256) void finalize_offsets(int* __restrict__ row_off,
                                                        const int* __restrict__ blk_sums,
                                                        int* __restrict__ cursor,
                                                        const int* __restrict__ deg_out,
                                                        const int* __restrict__ deg_in,
                                                        float* __restrict__ norm_src,
                                                        float* __restrict__ norm_dst) {
    int idx = blockIdx.x * 256 + threadIdx.x;
    if (idx < N_NODES) {
        int ro = row_off[idx] + blk_sums[blockIdx.x];
        row_off[idx] = ro;
        cursor[idx]  = ro;
        int d_o = deg_out[idx];
        norm_src[idx] = rsqrtf((float)(d_o < 1 ? 1 : d_o));
        int d_i = deg_in[idx];
        norm_dst[idx] = rsqrtf((float)(d_i < 1 ? 1 : d_i));
    }
    if (idx == 0) row_off[N_NODES] = E_EDGES;
}

// ---------------------------------------------------------------------------
// bin: counting-sort edges by dst. int atomics only.
// ---------------------------------------------------------------------------
__global__ __launch_bounds__(256) void bin_kernel(const int* __restrict__ src,
                                                  const int* __restrict__ dst,
                                                  int* __restrict__ cursor,
                                                  int* __restrict__ edge_src) {
    int e = blockIdx.x * 256 + threadIdx.x;
    if (e < E_EDGES) {
        int pos = atomicAdd(&cursor[dst[e]], 1);
        edge_src[pos] = src[e];
    }
}

// ---------------------------------------------------------------------------
// GEMM: h0[n][c] = sum_f A[n][f] * W[c][f] + bias[c]
// BM=64 rows, BN=64 cols (= all of C), BK=32. 256 threads, 4x4 microtile.
// ---------------------------------------------------------------------------
__global__ __launch_bounds__(256) void gemm_kernel(const float* __restrict__ A,
                                                   const float* __restrict__ W,
                                                   const float* __restrict__ bias,
                                                   float* __restrict__ h0) {
    __shared__ float As[32][64];   // [k][m]
    __shared__ float Bs[32][64];   // [k][c]  (Bs[k][c] = W[c][k0+k])

    const int tid = threadIdx.x;
    const int tx = tid & 15;       // col group 0..15
    const int ty = tid >> 4;       // row group 0..15
    const int row0 = blockIdx.x * 64;

    float acc[4][4] = {};

    for (int k0 = 0; k0 < F_IN; k0 += 32) {
        {
            int r  = tid >> 3;            // 0..31
            int c4 = (tid & 7) * 4;       // 0..28
            #pragma unroll
            for (int half = 0; half < 2; ++half) {
                int rr = r + half * 32;
                int grow = row0 + rr;
                float4 v = make_float4(0.f, 0.f, 0.f, 0.f);
                if (grow < N_NODES)
                    v = *reinterpret_cast<const float4*>(&A[(size_t)grow * F_IN + k0 + c4]);
                As[c4 + 0][rr] = v.x;
                As[c4 + 1][rr] = v.y;
                As[c4 + 2][rr] = v.z;
                As[c4 + 3][rr] = v.w;
            }
        }
        {
            int c   = tid >> 2;           // 0..63
            int kk8 = (tid & 3) * 8;      // 0,8,16,24
            float4 v0 = *reinterpret_cast<const float4*>(&W[(size_t)c * F_IN + k0 + kk8]);
            float4 v1 = *reinterpret_cast<const float4*>(&W[(size_t)c * F_IN + k0 + kk8 + 4]);
            Bs[kk8 + 0][c] = v0.x;
            Bs[kk8 + 1][c] = v0.y;
            Bs[kk8 + 2][c] = v0.z;
            Bs[kk8 + 3][c] = v0.w;
            Bs[kk8 + 4][c] = v1.x;
            Bs[kk8 + 5][c] = v1.y;
            Bs[kk8 + 6][c] = v1.z;
            Bs[kk8 + 7][c] = v1.w;
        }
        __syncthreads();

        #pragma unroll
        for (int kk = 0; kk < 32; ++kk) {
            float4 a = *reinterpret_cast<const float4*>(&As[kk][ty * 4]);
            float4 b = *reinterpret_cast<const float4*>(&Bs[kk][tx * 4]);
            acc[0][0] += a.x * b.x; acc[0][1] += a.x * b.y; acc[0][2] += a.x * b.z; acc[0][3] += a.x * b.w;
            acc[1][0] += a.y * b.x; acc[1][1] += a.y * b.y; acc[1][2] += a.y * b.z; acc[1][3] += a.y * b.w;
            acc[2][0] += a.z * b.x; acc[2][1] += a.z * b.y; acc[2][2] += a.z * b.z; acc[2][3] += a.z * b.w;
            acc[3][0] += a.w * b.x; acc[3][1] += a.w * b.y; acc[3][2] += a.w * b.z; acc[3][3] += a.w * b.w;
        }
        __syncthreads();
    }

    float bx = bias[tx * 4 + 0];
    float by = bias[tx * 4 + 1];
    float bz = bias[tx * 4 + 2];
    float bw = bias[tx * 4 + 3];
    #pragma unroll
    for (int i = 0; i < 4; ++i) {
        int grow = row0 + ty * 4 + i;
        if (grow < N_NODES) {
            float4 o;
            o.x = acc[i][0] + bx;
            o.y = acc[i][1] + by;
            o.z = acc[i][2] + bz;
            o.w = acc[i][3] + bw;
            *reinterpret_cast<float4*>(&h0[(size_t)grow * C_OUT + tx * 4]) = o;
        }
    }
}

// ---------------------------------------------------------------------------
// gather: one wave64 per dst node, lane = channel. Zero atomics.
// out[n][c] = 0.8 * norm_dst[n] * sum_{e in seg(n)} h0[src_e][c]*norm_src[src_e]
//           + 0.2 * h0[n][c]
// ---------------------------------------------------------------------------
__global__ __launch_bounds__(256) void gather_kernel(const int* __restrict__ row_off,
                                                     const int* __restrict__ edge_src,
                                                     const float* __restrict__ h0,
                                                     const float* __restrict__ norm_src,
                                                     const float* __restrict__ norm_dst,
                                                     float* __restrict__ out) {
    int node = blockIdx.x * 4 + (threadIdx.x >> 6);
    int lane = threadIdx.x & 63;
    if (node >= N_NODES) return;

    int beg = row_off[node];
    int end = row_off[node + 1];
    float acc = 0.0f;
    int i = beg;
    for (; i + 1 < end; i += 2) {
        int s0 = edge_src[i];
        int s1 = edge_src[i + 1];
        float n0 = norm_src[s0];
        float n1 = norm_src[s1];
        float v0 = h0[s0 * C_OUT + lane];
        float v1 = h0[s1 * C_OUT + lane];
        acc += v0 * n0 + v1 * n1;
    }
    if (i < end) {
        int s = edge_src[i];
        acc += h0[s * C_OUT + lane] * norm_src[s];
    }
    float h = h0[node * C_OUT + lane];
    out[node * C_OUT + lane] = 0.8f * norm_dst[node] * acc + 0.2f * h;
}

// ---------------------------------------------------------------------------
extern "C" void kernel_launch(void* const* d_in, const int* in_sizes, int n_in,
                              void* d_out, int out_size, void* d_ws, size_t ws_size,
                              hipStream_t stream) {
    const float* in_feat = (const float*)d_in[0];   // [N, 512]
    const float* W       = (const float*)d_in[1];   // [64, 512]
    const float* bias    = (const float*)d_in[2];   // [64]
    const int*   src     = (const int*)d_in[3];     // [E]
    const int*   dst     = (const int*)d_in[4];     // [E]
    float* out = (float*)d_out;                     // [N, 64]

    // workspace layout (all 4B elements):
    float* h0       = (float*)d_ws;                          // N*64
    int*   edge_src = (int*)(h0 + (size_t)N_NODES * C_OUT);  // E
    int*   row_off  = edge_src + E_EDGES;                    // N+1
    int*   cursor   = row_off + N_NODES + 1;                 // N
    int*   deg_out  = cursor + N_NODES;                      // N
    int*   deg_in   = deg_out + N_NODES;                     // N
    float* norm_src = (float*)(deg_in + N_NODES);            // N
    float* norm_dst = norm_src + N_NODES;                    // N
    int*   blk_sums = (int*)(norm_dst + N_NODES);            // NBLK

    zero_kernel<<<NBLK, 256, 0, stream>>>(deg_out, deg_in);
    degree_kernel<<<(E_EDGES + 255) / 256, 256, 0, stream>>>(src, dst, deg_out, deg_in);
    scan_block<<<NBLK, 256, 0, stream>>>(deg_in, row_off, blk_sums);
    scan_tops<<<1, 512, 0, stream>>>(blk_sums);
    finalize_offsets<<<NBLK, 256, 0, stream>>>(row_off, blk_sums, cursor,
                                               deg_out, deg_in, norm_src, norm_dst);
    bin_kernel<<<(E_EDGES + 255) / 256, 256, 0, stream>>>(src, dst, cursor, edge_src);
    gemm_kernel<<<(N_NODES + 63) / 64, 256, 0, stream>>>(in_feat, W, bias, h0);
    gather_kernel<<<(N_NODES + 3) / 4, 256, 0, stream>>>(row_off, edge_src, h0,
                                                         norm_src, norm_dst, out);
}

// Round 4
// 729.920 us; speedup vs baseline: 4.5241x; 1.4114x over previous
//
#include <hip/hip_runtime.h>

#define N_NODES 100000
#define E_EDGES 3200000
#define F_IN    512
#define C_OUT   64
#define NB      391     // coarse buckets: dst >> 8  (256 nodes per bucket)
#define TILE    4096    // edges per block in P0/P2
#define NTILE   782     // ceil(E / TILE)
#define NBLK    391     // ceil(N / 256)

// ---------------------------------------------------------------------------
// zero: deg_out (per-node out-degree) and bucket_cnt
// ---------------------------------------------------------------------------
__global__ __launch_bounds__(256) void zero_kernel(int* __restrict__ deg_out,
                                                   int* __restrict__ bucket_cnt) {
    int idx = blockIdx.x * 256 + threadIdx.x;
    if (idx < N_NODES) deg_out[idx] = 0;
    if (idx < NB) bucket_cnt[idx] = 0;
}

// ---------------------------------------------------------------------------
// P0: coarse-bucket histogram of dst (LDS-staged) + deg_out histogram of src
// ---------------------------------------------------------------------------
__global__ __launch_bounds__(256) void p0_hist(const int* __restrict__ src,
                                               const int* __restrict__ dst,
                                               int* __restrict__ deg_out,
                                               int* __restrict__ bucket_cnt) {
    __shared__ int cnt[NB];
    for (int j = threadIdx.x; j < NB; j += 256) cnt[j] = 0;
    __syncthreads();
    int base = blockIdx.x * TILE;
    #pragma unroll 4
    for (int i = 0; i < 16; ++i) {
        int e = base + i * 256 + threadIdx.x;
        if (e < E_EDGES) {
            atomicAdd(&deg_out[src[e]], 1);
            atomicAdd(&cnt[dst[e] >> 8], 1);
        }
    }
    __syncthreads();
    for (int j = threadIdx.x; j < NB; j += 256) {
        int c = cnt[j];
        if (c) atomicAdd(&bucket_cnt[j], c);
    }
}

// ---------------------------------------------------------------------------
// P1: single-block exclusive scan of bucket_cnt -> bucket_base[0..NB], cursor
// ---------------------------------------------------------------------------
__global__ __launch_bounds__(512) void p1_scan(const int* __restrict__ bucket_cnt,
                                               int* __restrict__ bucket_base,
                                               int* __restrict__ cursor,
                                               int* __restrict__ row_off) {
    __shared__ int s[512];
    int t = threadIdx.x;
    int v = (t < NB) ? bucket_cnt[t] : 0;
    s[t] = v;
    __syncthreads();
    #pragma unroll
    for (int off = 1; off < 512; off <<= 1) {
        int add = (t >= off) ? s[t - off] : 0;
        __syncthreads();
        s[t] += add;
        __syncthreads();
    }
    int excl = s[t] - v;           // exclusive prefix (t >= NB: == E)
    if (t <= NB) bucket_base[t] = excl;
    if (t < NB)  cursor[t] = excl;
    if (t == 0)  row_off[N_NODES] = E_EDGES;
}

// ---------------------------------------------------------------------------
// P2: partition edges into coarse buckets. One global atomic per (block,bucket)
// reserves a contiguous run -> block-contiguous packed writes.
// payload: (dst & 255) << 24 | src   (src < 2^17 fits in low 24 bits)
// ---------------------------------------------------------------------------
__global__ __launch_bounds__(256) void p2_part(const int* __restrict__ src,
                                               const int* __restrict__ dst,
                                               int* __restrict__ cursor,
                                               unsigned int* __restrict__ tmp) {
    __shared__ int cnt[NB];
    __shared__ int base[NB];
    for (int j = threadIdx.x; j < NB; j += 256) cnt[j] = 0;
    __syncthreads();
    int tb = blockIdx.x * TILE;
    unsigned int v[16];
    int bb[16];
    #pragma unroll 4
    for (int i = 0; i < 16; ++i) {
        int e = tb + i * 256 + threadIdx.x;
        bb[i] = -1;
        if (e < E_EDGES) {
            int s = src[e], d = dst[e];
            bb[i] = d >> 8;
            v[i] = ((unsigned int)(d & 255) << 24) | (unsigned int)s;
            atomicAdd(&cnt[bb[i]], 1);
        }
    }
    __syncthreads();
    for (int j = threadIdx.x; j < NB; j += 256) {
        int c = cnt[j];
        base[j] = c ? atomicAdd(&cursor[j], c) : 0;
        cnt[j] = 0;                  // reuse as local cursor
    }
    __syncthreads();
    #pragma unroll 4
    for (int i = 0; i < 16; ++i) {
        if (bb[i] >= 0) {
            int p = atomicAdd(&cnt[bb[i]], 1);
            tmp[base[bb[i]] + p] = v[i];
        }
    }
}

// ---------------------------------------------------------------------------
// P3: one block per bucket. Local histogram + scan -> row_off, norms, and
// scatter src into final CSR slots (all writes inside a 32KB L2 window).
// ---------------------------------------------------------------------------
__global__ __launch_bounds__(256) void p3_build(const unsigned int* __restrict__ tmp,
                                                const int* __restrict__ bucket_base,
                                                const int* __restrict__ deg_out,
                                                int* __restrict__ row_off,
                                                int* __restrict__ edge_src,
                                                float* __restrict__ norm_src,
                                                float* __restrict__ norm_dst) {
    __shared__ int cnt[256];
    __shared__ int off[256];
    __shared__ int lc[256];
    __shared__ int s[256];
    int t = threadIdx.x;
    int b = blockIdx.x;
    int bbase = bucket_base[b];
    int bend  = bucket_base[b + 1];
    cnt[t] = 0;
    lc[t] = 0;
    __syncthreads();
    for (int e = bbase + t; e < bend; e += 256)
        atomicAdd(&cnt[tmp[e] >> 24], 1);
    __syncthreads();
    int vv = cnt[t];
    s[t] = vv;
    __syncthreads();
    #pragma unroll
    for (int o = 1; o < 256; o <<= 1) {
        int add = (t >= o) ? s[t - o] : 0;
        __syncthreads();
        s[t] += add;
        __syncthreads();
    }
    off[t] = s[t] - vv;             // exclusive prefix within bucket
    __syncthreads();
    int node = b * 256 + t;
    if (node < N_NODES) {
        row_off[node] = bbase + off[t];
        norm_dst[node] = rsqrtf((float)(vv < 1 ? 1 : vv));
        int dg = deg_out[node];
        norm_src[node] = rsqrtf((float)(dg < 1 ? 1 : dg));
    }
    for (int e = bbase + t; e < bend; e += 256) {
        unsigned int v = tmp[e];
        int dl = v >> 24;
        int p = atomicAdd(&lc[dl], 1);
        edge_src[bbase + off[dl] + p] = (int)(v & 0x00FFFFFFu);  // FIX: full 24-bit src
    }
}

// ---------------------------------------------------------------------------
// GEMM: h0[n][c] = sum_f A[n][f] * W[c][f] + bias[c]
// ---------------------------------------------------------------------------
__global__ __launch_bounds__(256) void gemm_kernel(const float* __restrict__ A,
                                                   const float* __restrict__ W,
                                                   const float* __restrict__ bias,
                                                   float* __restrict__ h0) {
    __shared__ float As[32][64];   // [k][m]
    __shared__ float Bs[32][64];   // [k][c]

    const int tid = threadIdx.x;
    const int tx = tid & 15;
    const int ty = tid >> 4;
    const int row0 = blockIdx.x * 64;

    float acc[4][4] = {};

    for (int k0 = 0; k0 < F_IN; k0 += 32) {
        {
            int r  = tid >> 3;
            int c4 = (tid & 7) * 4;
            #pragma unroll
            for (int half = 0; half < 2; ++half) {
                int rr = r + half * 32;
                int grow = row0 + rr;
                float4 v = make_float4(0.f, 0.f, 0.f, 0.f);
                if (grow < N_NODES)
                    v = *reinterpret_cast<const float4*>(&A[(size_t)grow * F_IN + k0 + c4]);
                As[c4 + 0][rr] = v.x;
                As[c4 + 1][rr] = v.y;
                As[c4 + 2][rr] = v.z;
                As[c4 + 3][rr] = v.w;
            }
        }
        {
            int c   = tid >> 2;
            int kk8 = (tid & 3) * 8;
            float4 v0 = *reinterpret_cast<const float4*>(&W[(size_t)c * F_IN + k0 + kk8]);
            float4 v1 = *reinterpret_cast<const float4*>(&W[(size_t)c * F_IN + k0 + kk8 + 4]);
            Bs[kk8 + 0][c] = v0.x;
            Bs[kk8 + 1][c] = v0.y;
            Bs[kk8 + 2][c] = v0.z;
            Bs[kk8 + 3][c] = v0.w;
            Bs[kk8 + 4][c] = v1.x;
            Bs[kk8 + 5][c] = v1.y;
            Bs[kk8 + 6][c] = v1.z;
            Bs[kk8 + 7][c] = v1.w;
        }
        __syncthreads();

        #pragma unroll
        for (int kk = 0; kk < 32; ++kk) {
            float4 a = *reinterpret_cast<const float4*>(&As[kk][ty * 4]);
            float4 b = *reinterpret_cast<const float4*>(&Bs[kk][tx * 4]);
            acc[0][0] += a.x * b.x; acc[0][1] += a.x * b.y; acc[0][2] += a.x * b.z; acc[0][3] += a.x * b.w;
            acc[1][0] += a.y * b.x; acc[1][1] += a.y * b.y; acc[1][2] += a.y * b.z; acc[1][3] += a.y * b.w;
            acc[2][0] += a.z * b.x; acc[2][1] += a.z * b.y; acc[2][2] += a.z * b.z; acc[2][3] += a.z * b.w;
            acc[3][0] += a.w * b.x; acc[3][1] += a.w * b.y; acc[3][2] += a.w * b.z; acc[3][3] += a.w * b.w;
        }
        __syncthreads();
    }

    float bx = bias[tx * 4 + 0];
    float by = bias[tx * 4 + 1];
    float bz = bias[tx * 4 + 2];
    float bw = bias[tx * 4 + 3];
    #pragma unroll
    for (int i = 0; i < 4; ++i) {
        int grow = row0 + ty * 4 + i;
        if (grow < N_NODES) {
            float4 o;
            o.x = acc[i][0] + bx;
            o.y = acc[i][1] + by;
            o.z = acc[i][2] + bz;
            o.w = acc[i][3] + bw;
            *reinterpret_cast<float4*>(&h0[(size_t)grow * C_OUT + tx * 4]) = o;
        }
    }
}

// ---------------------------------------------------------------------------
// gather: one wave64 per dst node, lane = channel. Zero atomics.
// ---------------------------------------------------------------------------
__global__ __launch_bounds__(256) void gather_kernel(const int* __restrict__ row_off,
                                                     const int* __restrict__ edge_src,
                                                     const float* __restrict__ h0,
                                                     const float* __restrict__ norm_src,
                                                     const float* __restrict__ norm_dst,
                                                     float* __restrict__ out) {
    int node = blockIdx.x * 4 + (threadIdx.x >> 6);
    int lane = threadIdx.x & 63;
    if (node >= N_NODES) return;

    int beg = row_off[node];
    int end = row_off[node + 1];
    float acc = 0.0f;
    int i = beg;
    for (; i + 1 < end; i += 2) {
        int s0 = edge_src[i];
        int s1 = edge_src[i + 1];
        float n0 = norm_src[s0];
        float n1 = norm_src[s1];
        float v0 = h0[s0 * C_OUT + lane];
        float v1 = h0[s1 * C_OUT + lane];
        acc += v0 * n0 + v1 * n1;
    }
    if (i < end) {
        int s = edge_src[i];
        acc += h0[s * C_OUT + lane] * norm_src[s];
    }
    float h = h0[node * C_OUT + lane];
    out[node * C_OUT + lane] = 0.8f * norm_dst[node] * acc + 0.2f * h;
}

// ---------------------------------------------------------------------------
extern "C" void kernel_launch(void* const* d_in, const int* in_sizes, int n_in,
                              void* d_out, int out_size, void* d_ws, size_t ws_size,
                              hipStream_t stream) {
    const float* in_feat = (const float*)d_in[0];   // [N, 512]
    const float* W       = (const float*)d_in[1];   // [64, 512]
    const float* bias    = (const float*)d_in[2];   // [64]
    const int*   src     = (const int*)d_in[3];     // [E]
    const int*   dst     = (const int*)d_in[4];     // [E]
    float* out = (float*)d_out;                     // [N, 64]

    // workspace layout:
    //   h0 (N*64 f32, 25.6MB)  -- tmp (E u32, 12.8MB) aliases its start
    //   edge_src (E i32) | row_off (N+1) | deg_out (N) | norm_src (N) |
    //   norm_dst (N) | bucket_cnt (NB) | bucket_base (NB+1) | cursor (NB)
    float*        h0       = (float*)d_ws;
    unsigned int* tmp      = (unsigned int*)d_ws;              // aliases h0
    int*   edge_src = (int*)(h0 + (size_t)N_NODES * C_OUT);
    int*   row_off  = edge_src + E_EDGES;
    int*   deg_out  = row_off + N_NODES + 1;
    float* norm_src = (float*)(deg_out + N_NODES);
    float* norm_dst = norm_src + N_NODES;
    int*   bucket_cnt  = (int*)(norm_dst + N_NODES);
    int*   bucket_base = bucket_cnt + NB;
    int*   cursor      = bucket_base + NB + 1;

    zero_kernel<<<NBLK, 256, 0, stream>>>(deg_out, bucket_cnt);
    p0_hist<<<NTILE, 256, 0, stream>>>(src, dst, deg_out, bucket_cnt);
    p1_scan<<<1, 512, 0, stream>>>(bucket_cnt, bucket_base, cursor, row_off);
    p2_part<<<NTILE, 256, 0, stream>>>(src, dst, cursor, tmp);
    p3_build<<<NB, 256, 0, stream>>>(tmp, bucket_base, deg_out, row_off,
                                     edge_src, norm_src, norm_dst);
    // gemm AFTER p3: h0 overwrites tmp's memory only once tmp is consumed
    gemm_kernel<<<(N_NODES + 63) / 64, 256, 0, stream>>>(in_feat, W, bias, h0);
    gather_kernel<<<(N_NODES + 3) / 4, 256, 0, stream>>>(row_off, edge_src, h0,
                                                         norm_src, norm_dst, out);
}

// Round 5
// 635.020 us; speedup vs baseline: 5.2002x; 1.1494x over previous
//
#include <hip/hip_runtime.h>

#define N_NODES 100000
#define E_EDGES 3200000
#define F_IN    512
#define C_OUT   64
#define NB      391     // coarse buckets: dst >> 8  (256 nodes per bucket)
#define TILE    4096    // edges per block in P0/P2
#define NTILE   782     // ceil(E / TILE)
#define NBLK    391     // ceil(N / 256)

typedef __bf16 bf16x8 __attribute__((ext_vector_type(8)));
typedef float  f32x4  __attribute__((ext_vector_type(4)));

// fp32 -> bf16 (round-to-nearest-even), bit-level
static __device__ __forceinline__ unsigned short f2bf(float f) {
    unsigned int u = __float_as_uint(f);
    u = (u + 0x7FFFu + ((u >> 16) & 1u)) >> 16;
    return (unsigned short)u;
}
// bf16 bits -> fp32 (exact)
static __device__ __forceinline__ float bf2f(unsigned short b) {
    return __uint_as_float(((unsigned int)b) << 16);
}

// ---------------------------------------------------------------------------
// zero: deg_out (per-node out-degree) and bucket_cnt
// ---------------------------------------------------------------------------
__global__ __launch_bounds__(256) void zero_kernel(int* __restrict__ deg_out,
                                                   int* __restrict__ bucket_cnt) {
    int idx = blockIdx.x * 256 + threadIdx.x;
    if (idx < N_NODES) deg_out[idx] = 0;
    if (idx < NB) bucket_cnt[idx] = 0;
}

// ---------------------------------------------------------------------------
// P0: coarse-bucket histogram of dst (LDS-staged) + deg_out histogram of src
// ---------------------------------------------------------------------------
__global__ __launch_bounds__(256) void p0_hist(const int* __restrict__ src,
                                               const int* __restrict__ dst,
                                               int* __restrict__ deg_out,
                                               int* __restrict__ bucket_cnt) {
    __shared__ int cnt[NB];
    for (int j = threadIdx.x; j < NB; j += 256) cnt[j] = 0;
    __syncthreads();
    int base = blockIdx.x * TILE;
    #pragma unroll 4
    for (int i = 0; i < 16; ++i) {
        int e = base + i * 256 + threadIdx.x;
        if (e < E_EDGES) {
            atomicAdd(&deg_out[src[e]], 1);
            atomicAdd(&cnt[dst[e] >> 8], 1);
        }
    }
    __syncthreads();
    for (int j = threadIdx.x; j < NB; j += 256) {
        int c = cnt[j];
        if (c) atomicAdd(&bucket_cnt[j], c);
    }
}

// ---------------------------------------------------------------------------
// P1: single-block exclusive scan of bucket_cnt -> bucket_base[0..NB], cursor
// ---------------------------------------------------------------------------
__global__ __launch_bounds__(512) void p1_scan(const int* __restrict__ bucket_cnt,
                                               int* __restrict__ bucket_base,
                                               int* __restrict__ cursor,
                                               int* __restrict__ row_off) {
    __shared__ int s[512];
    int t = threadIdx.x;
    int v = (t < NB) ? bucket_cnt[t] : 0;
    s[t] = v;
    __syncthreads();
    #pragma unroll
    for (int off = 1; off < 512; off <<= 1) {
        int add = (t >= off) ? s[t - off] : 0;
        __syncthreads();
        s[t] += add;
        __syncthreads();
    }
    int excl = s[t] - v;
    if (t <= NB) bucket_base[t] = excl;
    if (t < NB)  cursor[t] = excl;
    if (t == 0)  row_off[N_NODES] = E_EDGES;
}

// ---------------------------------------------------------------------------
// P2: partition edges into coarse buckets. One global atomic per (block,bucket)
// payload: (dst & 255) << 24 | src
// ---------------------------------------------------------------------------
__global__ __launch_bounds__(256) void p2_part(const int* __restrict__ src,
                                               const int* __restrict__ dst,
                                               int* __restrict__ cursor,
                                               unsigned int* __restrict__ tmp) {
    __shared__ int cnt[NB];
    __shared__ int base[NB];
    for (int j = threadIdx.x; j < NB; j += 256) cnt[j] = 0;
    __syncthreads();
    int tb = blockIdx.x * TILE;
    unsigned int v[16];
    int bb[16];
    #pragma unroll 4
    for (int i = 0; i < 16; ++i) {
        int e = tb + i * 256 + threadIdx.x;
        bb[i] = -1;
        if (e < E_EDGES) {
            int s = src[e], d = dst[e];
            bb[i] = d >> 8;
            v[i] = ((unsigned int)(d & 255) << 24) | (unsigned int)s;
            atomicAdd(&cnt[bb[i]], 1);
        }
    }
    __syncthreads();
    for (int j = threadIdx.x; j < NB; j += 256) {
        int c = cnt[j];
        base[j] = c ? atomicAdd(&cursor[j], c) : 0;
        cnt[j] = 0;
    }
    __syncthreads();
    #pragma unroll 4
    for (int i = 0; i < 16; ++i) {
        if (bb[i] >= 0) {
            int p = atomicAdd(&cnt[bb[i]], 1);
            tmp[base[bb[i]] + p] = v[i];
        }
    }
}

// ---------------------------------------------------------------------------
// P3: one block per bucket -> row_off, norms, final CSR edge_src
// ---------------------------------------------------------------------------
__global__ __launch_bounds__(256) void p3_build(const unsigned int* __restrict__ tmp,
                                                const int* __restrict__ bucket_base,
                                                const int* __restrict__ deg_out,
                                                int* __restrict__ row_off,
                                                int* __restrict__ edge_src,
                                                float* __restrict__ norm_src,
                                                float* __restrict__ norm_dst) {
    __shared__ int cnt[256];
    __shared__ int off[256];
    __shared__ int lc[256];
    __shared__ int s[256];
    int t = threadIdx.x;
    int b = blockIdx.x;
    int bbase = bucket_base[b];
    int bend  = bucket_base[b + 1];
    cnt[t] = 0;
    lc[t] = 0;
    __syncthreads();
    for (int e = bbase + t; e < bend; e += 256)
        atomicAdd(&cnt[tmp[e] >> 24], 1);
    __syncthreads();
    int vv = cnt[t];
    s[t] = vv;
    __syncthreads();
    #pragma unroll
    for (int o = 1; o < 256; o <<= 1) {
        int add = (t >= o) ? s[t - o] : 0;
        __syncthreads();
        s[t] += add;
        __syncthreads();
    }
    off[t] = s[t] - vv;
    __syncthreads();
    int node = b * 256 + t;
    if (node < N_NODES) {
        row_off[node] = bbase + off[t];
        norm_dst[node] = rsqrtf((float)(vv < 1 ? 1 : vv));
        int dg = deg_out[node];
        norm_src[node] = rsqrtf((float)(dg < 1 ? 1 : dg));
    }
    for (int e = bbase + t; e < bend; e += 256) {
        unsigned int v = tmp[e];
        int dl = v >> 24;
        int p = atomicAdd(&lc[dl], 1);
        edge_src[bbase + off[dl] + p] = (int)(v & 0x00FFFFFFu);
    }
}

// ---------------------------------------------------------------------------
// GEMM (bf16 MFMA): h0b[n][c] = bf16( sum_f A[n][f]*W[c][f] + bias[c] )
// Block: 256 thr = 4 waves, 64 rows. Wave w: rows [row0+w*16, +16), all 64 cols
// via 4 col-tiles of 16. mfma_f32_16x16x32_bf16:
//   A-frag: A[m=lane&15][k=quad*8+j]   B-frag: B[k=quad*8+j][n=lane&15]
//   D:      row=quad*4+reg, col=lane&15
// W is converted once to bf16 in LDS (row stride 520 to break bank aliasing).
// ---------------------------------------------------------------------------
__global__ __launch_bounds__(256) void gemm_kernel(const float* __restrict__ A,
                                                   const float* __restrict__ W,
                                                   const float* __restrict__ bias,
                                                   unsigned short* __restrict__ h0b) {
    __shared__ unsigned short Wl[64 * 520];   // 66560 B

    const int tid  = threadIdx.x;
    const int w    = tid >> 6;
    const int lane = tid & 63;
    const int cl   = lane & 15;
    const int quad = lane >> 4;
    const int row0 = blockIdx.x * 64;

    // --- stage W -> LDS as bf16 (32768 elems, 128/thread as float4) ---
    #pragma unroll 8
    for (int j = 0; j < 32; ++j) {
        int e4 = (j * 256 + tid) * 4;             // element index
        float4 wv = *reinterpret_cast<const float4*>(&W[e4]);
        int c = e4 >> 9;
        int k = e4 & 511;
        unsigned short* d = &Wl[c * 520 + k];
        d[0] = f2bf(wv.x); d[1] = f2bf(wv.y); d[2] = f2bf(wv.z); d[3] = f2bf(wv.w);
    }
    __syncthreads();

    int arow = row0 + w * 16 + cl;
    if (arow >= N_NODES) arow = N_NODES - 1;      // clamp; guarded at store
    const float* aptr = A + (size_t)arow * F_IN + quad * 8;

    f32x4 acc0 = {0.f, 0.f, 0.f, 0.f};
    f32x4 acc1 = {0.f, 0.f, 0.f, 0.f};
    f32x4 acc2 = {0.f, 0.f, 0.f, 0.f};
    f32x4 acc3 = {0.f, 0.f, 0.f, 0.f};

    for (int k0 = 0; k0 < F_IN; k0 += 32) {
        float4 p = *reinterpret_cast<const float4*>(aptr + k0);
        float4 q = *reinterpret_cast<const float4*>(aptr + k0 + 4);
        bf16x8 af;
        af[0] = (__bf16)p.x; af[1] = (__bf16)p.y; af[2] = (__bf16)p.z; af[3] = (__bf16)p.w;
        af[4] = (__bf16)q.x; af[5] = (__bf16)q.y; af[6] = (__bf16)q.z; af[7] = (__bf16)q.w;

        const unsigned short* wb = &Wl[k0 + quad * 8];
        bf16x8 b0 = *reinterpret_cast<const bf16x8*>(wb + (cl +  0) * 520);
        bf16x8 b1 = *reinterpret_cast<const bf16x8*>(wb + (cl + 16) * 520);
        bf16x8 b2 = *reinterpret_cast<const bf16x8*>(wb + (cl + 32) * 520);
        bf16x8 b3 = *reinterpret_cast<const bf16x8*>(wb + (cl + 48) * 520);

        acc0 = __builtin_amdgcn_mfma_f32_16x16x32_bf16(af, b0, acc0, 0, 0, 0);
        acc1 = __builtin_amdgcn_mfma_f32_16x16x32_bf16(af, b1, acc1, 0, 0, 0);
        acc2 = __builtin_amdgcn_mfma_f32_16x16x32_bf16(af, b2, acc2, 0, 0, 0);
        acc3 = __builtin_amdgcn_mfma_f32_16x16x32_bf16(af, b3, acc3, 0, 0, 0);
    }

    // epilogue: bias + store bf16. D: row = quad*4 + r, col = ct*16 + cl
    float bias0 = bias[cl +  0];
    float bias1 = bias[cl + 16];
    float bias2 = bias[cl + 32];
    float bias3 = bias[cl + 48];
    #pragma unroll
    for (int r = 0; r < 4; ++r) {
        int row = row0 + w * 16 + quad * 4 + r;
        if (row < N_NODES) {
            unsigned short* o = &h0b[(size_t)row * C_OUT + cl];
            o[ 0] = f2bf(acc0[r] + bias0);
            o[16] = f2bf(acc1[r] + bias1);
            o[32] = f2bf(acc2[r] + bias2);
            o[48] = f2bf(acc3[r] + bias3);
        }
    }
}

// ---------------------------------------------------------------------------
// gather: one wave64 per dst node, lane = channel. bf16 h0, 4-edge ILP batches.
// ---------------------------------------------------------------------------
__global__ __launch_bounds__(256) void gather_kernel(const int* __restrict__ row_off,
                                                     const int* __restrict__ edge_src,
                                                     const unsigned short* __restrict__ h0b,
                                                     const float* __restrict__ norm_src,
                                                     const float* __restrict__ norm_dst,
                                                     float* __restrict__ out) {
    int node = blockIdx.x * 4 + (threadIdx.x >> 6);
    int lane = threadIdx.x & 63;
    if (node >= N_NODES) return;

    int beg = row_off[node];
    int end = row_off[node + 1];
    float acc = 0.0f;
    int i = beg;
    for (; i + 3 < end; i += 4) {
        int s0 = edge_src[i + 0];
        int s1 = edge_src[i + 1];
        int s2 = edge_src[i + 2];
        int s3 = edge_src[i + 3];
        float n0 = norm_src[s0];
        float n1 = norm_src[s1];
        float n2 = norm_src[s2];
        float n3 = norm_src[s3];
        float v0 = bf2f(h0b[s0 * C_OUT + lane]);
        float v1 = bf2f(h0b[s1 * C_OUT + lane]);
        float v2 = bf2f(h0b[s2 * C_OUT + lane]);
        float v3 = bf2f(h0b[s3 * C_OUT + lane]);
        acc += v0 * n0 + v1 * n1 + v2 * n2 + v3 * n3;
    }
    for (; i < end; ++i) {
        int s = edge_src[i];
        acc += bf2f(h0b[s * C_OUT + lane]) * norm_src[s];
    }
    float h = bf2f(h0b[node * C_OUT + lane]);
    out[node * C_OUT + lane] = 0.8f * norm_dst[node] * acc + 0.2f * h;
}

// ---------------------------------------------------------------------------
extern "C" void kernel_launch(void* const* d_in, const int* in_sizes, int n_in,
                              void* d_out, int out_size, void* d_ws, size_t ws_size,
                              hipStream_t stream) {
    const float* in_feat = (const float*)d_in[0];   // [N, 512]
    const float* W       = (const float*)d_in[1];   // [64, 512]
    const float* bias    = (const float*)d_in[2];   // [64]
    const int*   src     = (const int*)d_in[3];     // [E]
    const int*   dst     = (const int*)d_in[4];     // [E]
    float* out = (float*)d_out;                     // [N, 64]

    // workspace layout:
    //   h0b (N*64 bf16, 12.8MB) -- tmp (E u32, 12.8MB) aliases it exactly
    //   edge_src (E i32) | row_off (N+1) | deg_out (N) | norm_src (N) |
    //   norm_dst (N) | bucket_cnt (NB) | bucket_base (NB+1) | cursor (NB)
    unsigned short* h0b = (unsigned short*)d_ws;
    unsigned int*   tmp = (unsigned int*)d_ws;                 // aliases h0b
    int*   edge_src = (int*)((char*)d_ws + (size_t)N_NODES * C_OUT * 2);
    int*   row_off  = edge_src + E_EDGES;
    int*   deg_out  = row_off + N_NODES + 1;
    float* norm_src = (float*)(deg_out + N_NODES);
    float* norm_dst = norm_src + N_NODES;
    int*   bucket_cnt  = (int*)(norm_dst + N_NODES);
    int*   bucket_base = bucket_cnt + NB;
    int*   cursor      = bucket_base + NB + 1;

    zero_kernel<<<NBLK, 256, 0, stream>>>(deg_out, bucket_cnt);
    p0_hist<<<NTILE, 256, 0, stream>>>(src, dst, deg_out, bucket_cnt);
    p1_scan<<<1, 512, 0, stream>>>(bucket_cnt, bucket_base, cursor, row_off);
    p2_part<<<NTILE, 256, 0, stream>>>(src, dst, cursor, tmp);
    p3_build<<<NB, 256, 0, stream>>>(tmp, bucket_base, deg_out, row_off,
                                     edge_src, norm_src, norm_dst);
    // gemm AFTER p3: h0b overwrites tmp's memory only once tmp is consumed
    gemm_kernel<<<(N_NODES + 63) / 64, 256, 0, stream>>>(in_feat, W, bias, h0b);
    gather_kernel<<<(N_NODES + 3) / 4, 256, 0, stream>>>(row_off, edge_src, h0b,
                                                         norm_src, norm_dst, out);
}

// Round 6
// 545.495 us; speedup vs baseline: 6.0536x; 1.1641x over previous
//
#include <hip/hip_runtime.h>

#define N_NODES 100000
#define E_EDGES 3200000
#define F_IN    512
#define C_OUT   64
#define NB      391     // coarse buckets: node >> 8  (256 nodes per bucket)
#define TILE    4096    // edges per block in P0/P2
#define NTILE   782     // ceil(E / TILE)

typedef __bf16 bf16x8 __attribute__((ext_vector_type(8)));
typedef float  f32x4  __attribute__((ext_vector_type(4)));

// fp32 -> bf16 (round-to-nearest-even), bit-level
static __device__ __forceinline__ unsigned short f2bf(float f) {
    unsigned int u = __float_as_uint(f);
    u = (u + 0x7FFFu + ((u >> 16) & 1u)) >> 16;
    return (unsigned short)u;
}
// bf16 bits -> fp32 (exact)
static __device__ __forceinline__ float bf2f(unsigned short b) {
    return __uint_as_float(((unsigned int)b) << 16);
}

// ---------------------------------------------------------------------------
// zero: bucket counter arrays only (no per-node arrays anymore)
// ---------------------------------------------------------------------------
__global__ __launch_bounds__(256) void zero_kernel(int* __restrict__ bc_dst,
                                                   int* __restrict__ bc_src) {
    int idx = blockIdx.x * 256 + threadIdx.x;
    if (idx < NB) { bc_dst[idx] = 0; bc_src[idx] = 0; }
}

// ---------------------------------------------------------------------------
// P0: LDS-staged coarse-bucket histograms of dst>>8 and src>>8.
// ZERO per-node global atomics (the round-5 bottleneck: 101 MB WRITE_SIZE).
// ---------------------------------------------------------------------------
__global__ __launch_bounds__(256) void p0_hist(const int* __restrict__ src,
                                               const int* __restrict__ dst,
                                               int* __restrict__ bc_dst,
                                               int* __restrict__ bc_src) {
    __shared__ int cd[NB];
    __shared__ int cs[NB];
    for (int j = threadIdx.x; j < NB; j += 256) { cd[j] = 0; cs[j] = 0; }
    __syncthreads();
    int base = blockIdx.x * TILE;
    #pragma unroll 4
    for (int i = 0; i < 16; ++i) {
        int e = base + i * 256 + threadIdx.x;
        if (e < E_EDGES) {
            atomicAdd(&cd[dst[e] >> 8], 1);
            atomicAdd(&cs[src[e] >> 8], 1);
        }
    }
    __syncthreads();
    for (int j = threadIdx.x; j < NB; j += 256) {
        int c = cd[j];
        if (c) atomicAdd(&bc_dst[j], c);
        c = cs[j];
        if (c) atomicAdd(&bc_src[j], c);
    }
}

// ---------------------------------------------------------------------------
// P1: single-block exclusive scans of both bucket-count arrays
// ---------------------------------------------------------------------------
__global__ __launch_bounds__(512) void p1_scan(const int* __restrict__ bc_dst,
                                               const int* __restrict__ bc_src,
                                               int* __restrict__ base_d,
                                               int* __restrict__ cursor_d,
                                               int* __restrict__ base_s,
                                               int* __restrict__ cursor_s,
                                               int* __restrict__ row_off) {
    __shared__ int s[512];
    int t = threadIdx.x;
    // --- dst buckets ---
    int v = (t < NB) ? bc_dst[t] : 0;
    s[t] = v;
    __syncthreads();
    #pragma unroll
    for (int off = 1; off < 512; off <<= 1) {
        int add = (t >= off) ? s[t - off] : 0;
        __syncthreads();
        s[t] += add;
        __syncthreads();
    }
    int excl = s[t] - v;
    if (t <= NB) base_d[t] = excl;
    if (t < NB)  cursor_d[t] = excl;
    __syncthreads();
    // --- src buckets ---
    int v2 = (t < NB) ? bc_src[t] : 0;
    s[t] = v2;
    __syncthreads();
    #pragma unroll
    for (int off = 1; off < 512; off <<= 1) {
        int add = (t >= off) ? s[t - off] : 0;
        __syncthreads();
        s[t] += add;
        __syncthreads();
    }
    int excl2 = s[t] - v2;
    if (t <= NB) base_s[t] = excl2;
    if (t < NB)  cursor_s[t] = excl2;
    if (t == 0)  row_off[N_NODES] = E_EDGES;
}

// ---------------------------------------------------------------------------
// P2: dual partition. dst-partition -> tmp (u32: (dst&255)<<24 | src);
// src-partition -> tmp2 (u8: src&255). One global atomic per (block,bucket).
// ---------------------------------------------------------------------------
__global__ __launch_bounds__(256) void p2_part(const int* __restrict__ src,
                                               const int* __restrict__ dst,
                                               int* __restrict__ cursor_d,
                                               int* __restrict__ cursor_s,
                                               unsigned int* __restrict__ tmp,
                                               unsigned char* __restrict__ tmp2) {
    __shared__ int cntd[NB];
    __shared__ int based[NB];
    __shared__ int cnts[NB];
    __shared__ int bases[NB];
    for (int j = threadIdx.x; j < NB; j += 256) { cntd[j] = 0; cnts[j] = 0; }
    __syncthreads();
    int tb = blockIdx.x * TILE;
    unsigned int v[16];
    int bb[16];
    #pragma unroll 4
    for (int i = 0; i < 16; ++i) {
        int e = tb + i * 256 + threadIdx.x;
        bb[i] = -1;
        if (e < E_EDGES) {
            int s = src[e], d = dst[e];
            bb[i] = d >> 8;
            v[i] = ((unsigned int)(d & 255) << 24) | (unsigned int)s;
            atomicAdd(&cntd[bb[i]], 1);
            atomicAdd(&cnts[s >> 8], 1);
        }
    }
    __syncthreads();
    for (int j = threadIdx.x; j < NB; j += 256) {
        int c = cntd[j];
        based[j] = c ? atomicAdd(&cursor_d[j], c) : 0;
        cntd[j] = 0;
        c = cnts[j];
        bases[j] = c ? atomicAdd(&cursor_s[j], c) : 0;
        cnts[j] = 0;
    }
    __syncthreads();
    #pragma unroll 4
    for (int i = 0; i < 16; ++i) {
        if (bb[i] >= 0) {
            int p = atomicAdd(&cntd[bb[i]], 1);
            tmp[based[bb[i]] + p] = v[i];
            int sv = (int)(v[i] & 0x00FFFFFFu);
            int sbk = sv >> 8;
            int p2 = atomicAdd(&cnts[sbk], 1);
            tmp2[bases[sbk] + p2] = (unsigned char)(sv & 255);
        }
    }
}

// ---------------------------------------------------------------------------
// P3: block b owns nodes [256b, 256b+256). Builds dst-CSR (row_off, edge_src,
// norm_dst) AND out-degree histogram from tmp2 -> norm_src. No global atomics.
// ---------------------------------------------------------------------------
__global__ __launch_bounds__(256) void p3_build(const unsigned int* __restrict__ tmp,
                                                const unsigned char* __restrict__ tmp2,
                                                const int* __restrict__ base_d,
                                                const int* __restrict__ base_s,
                                                int* __restrict__ row_off,
                                                int* __restrict__ edge_src,
                                                float* __restrict__ norm_src,
                                                float* __restrict__ norm_dst) {
    __shared__ int cnt[256];
    __shared__ int off[256];
    __shared__ int lc[256];
    __shared__ int s[256];
    __shared__ int cnt2[256];
    int t = threadIdx.x;
    int b = blockIdx.x;
    int bbase = base_d[b];
    int bend  = base_d[b + 1];
    int sbase = base_s[b];
    int send  = base_s[b + 1];
    cnt[t] = 0;
    lc[t] = 0;
    cnt2[t] = 0;
    __syncthreads();
    for (int e = bbase + t; e < bend; e += 256)
        atomicAdd(&cnt[tmp[e] >> 24], 1);
    for (int e = sbase + t; e < send; e += 256)
        atomicAdd(&cnt2[tmp2[e]], 1);
    __syncthreads();
    int vv = cnt[t];
    s[t] = vv;
    __syncthreads();
    #pragma unroll
    for (int o = 1; o < 256; o <<= 1) {
        int add = (t >= o) ? s[t - o] : 0;
        __syncthreads();
        s[t] += add;
        __syncthreads();
    }
    off[t] = s[t] - vv;
    __syncthreads();
    int node = b * 256 + t;
    if (node < N_NODES) {
        row_off[node] = bbase + off[t];
        norm_dst[node] = rsqrtf((float)(vv < 1 ? 1 : vv));
        int dg = cnt2[t];
        norm_src[node] = rsqrtf((float)(dg < 1 ? 1 : dg));
    }
    for (int e = bbase + t; e < bend; e += 256) {
        unsigned int v = tmp[e];
        int dl = v >> 24;
        int p = atomicAdd(&lc[dl], 1);
        edge_src[bbase + off[dl] + p] = (int)(v & 0x00FFFFFFu);
    }
}

// ---------------------------------------------------------------------------
// GEMM (bf16 MFMA): h0b[n][c] = bf16( sum_f A[n][f]*W[c][f] + bias[c] )
// ---------------------------------------------------------------------------
__global__ __launch_bounds__(256) void gemm_kernel(const float* __restrict__ A,
                                                   const float* __restrict__ W,
                                                   const float* __restrict__ bias,
                                                   unsigned short* __restrict__ h0b) {
    __shared__ unsigned short Wl[64 * 520];   // 66560 B

    const int tid  = threadIdx.x;
    const int w    = tid >> 6;
    const int lane = tid & 63;
    const int cl   = lane & 15;
    const int quad = lane >> 4;
    const int row0 = blockIdx.x * 64;

    #pragma unroll 8
    for (int j = 0; j < 32; ++j) {
        int e4 = (j * 256 + tid) * 4;
        float4 wv = *reinterpret_cast<const float4*>(&W[e4]);
        int c = e4 >> 9;
        int k = e4 & 511;
        unsigned short* d = &Wl[c * 520 + k];
        d[0] = f2bf(wv.x); d[1] = f2bf(wv.y); d[2] = f2bf(wv.z); d[3] = f2bf(wv.w);
    }
    __syncthreads();

    int arow = row0 + w * 16 + cl;
    if (arow >= N_NODES) arow = N_NODES - 1;
    const float* aptr = A + (size_t)arow * F_IN + quad * 8;

    f32x4 acc0 = {0.f, 0.f, 0.f, 0.f};
    f32x4 acc1 = {0.f, 0.f, 0.f, 0.f};
    f32x4 acc2 = {0.f, 0.f, 0.f, 0.f};
    f32x4 acc3 = {0.f, 0.f, 0.f, 0.f};

    for (int k0 = 0; k0 < F_IN; k0 += 32) {
        float4 p = *reinterpret_cast<const float4*>(aptr + k0);
        float4 q = *reinterpret_cast<const float4*>(aptr + k0 + 4);
        bf16x8 af;
        af[0] = (__bf16)p.x; af[1] = (__bf16)p.y; af[2] = (__bf16)p.z; af[3] = (__bf16)p.w;
        af[4] = (__bf16)q.x; af[5] = (__bf16)q.y; af[6] = (__bf16)q.z; af[7] = (__bf16)q.w;

        const unsigned short* wb = &Wl[k0 + quad * 8];
        bf16x8 b0 = *reinterpret_cast<const bf16x8*>(wb + (cl +  0) * 520);
        bf16x8 b1 = *reinterpret_cast<const bf16x8*>(wb + (cl + 16) * 520);
        bf16x8 b2 = *reinterpret_cast<const bf16x8*>(wb + (cl + 32) * 520);
        bf16x8 b3 = *reinterpret_cast<const bf16x8*>(wb + (cl + 48) * 520);

        acc0 = __builtin_amdgcn_mfma_f32_16x16x32_bf16(af, b0, acc0, 0, 0, 0);
        acc1 = __builtin_amdgcn_mfma_f32_16x16x32_bf16(af, b1, acc1, 0, 0, 0);
        acc2 = __builtin_amdgcn_mfma_f32_16x16x32_bf16(af, b2, acc2, 0, 0, 0);
        acc3 = __builtin_amdgcn_mfma_f32_16x16x32_bf16(af, b3, acc3, 0, 0, 0);
    }

    float bias0 = bias[cl +  0];
    float bias1 = bias[cl + 16];
    float bias2 = bias[cl + 32];
    float bias3 = bias[cl + 48];
    #pragma unroll
    for (int r = 0; r < 4; ++r) {
        int row = row0 + w * 16 + quad * 4 + r;
        if (row < N_NODES) {
            unsigned short* o = &h0b[(size_t)row * C_OUT + cl];
            o[ 0] = f2bf(acc0[r] + bias0);
            o[16] = f2bf(acc1[r] + bias1);
            o[32] = f2bf(acc2[r] + bias2);
            o[48] = f2bf(acc3[r] + bias3);
        }
    }
}

// ---------------------------------------------------------------------------
// gather: one wave64 per dst node. 32 lanes x 2 channels (u32 of 2 bf16);
// two edge slots per wave (half = lane>>5), x4 unroll = 8 edges in flight.
// Halves combined via __shfl(lane^32); lanes 0..31 write float2.
// ---------------------------------------------------------------------------
__global__ __launch_bounds__(256) void gather_kernel(const int* __restrict__ row_off,
                                                     const int* __restrict__ edge_src,
                                                     const unsigned short* __restrict__ h0b,
                                                     const float* __restrict__ norm_src,
                                                     const float* __restrict__ norm_dst,
                                                     float* __restrict__ out) {
    int node = blockIdx.x * 4 + (threadIdx.x >> 6);
    int lane = threadIdx.x & 63;
    if (node >= N_NODES) return;
    int half = lane >> 5;          // edge slot 0/1
    int c2   = lane & 31;          // channel pair: channels 2*c2, 2*c2+1

    const unsigned int* h32 = reinterpret_cast<const unsigned int*>(h0b);

    int beg = row_off[node];
    int end = row_off[node + 1];
    float ax = 0.0f, ay = 0.0f;

    int base = beg;
    for (; base + 8 <= end; base += 8) {
        int e0 = base + half;
        int s0 = edge_src[e0 + 0];
        int s1 = edge_src[e0 + 2];
        int s2 = edge_src[e0 + 4];
        int s3 = edge_src[e0 + 6];
        float n0 = norm_src[s0];
        float n1 = norm_src[s1];
        float n2 = norm_src[s2];
        float n3 = norm_src[s3];
        unsigned int u0 = h32[s0 * 32 + c2];
        unsigned int u1 = h32[s1 * 32 + c2];
        unsigned int u2 = h32[s2 * 32 + c2];
        unsigned int u3 = h32[s3 * 32 + c2];
        ax += bf2f((unsigned short)u0) * n0 + bf2f((unsigned short)u1) * n1
            + bf2f((unsigned short)u2) * n2 + bf2f((unsigned short)u3) * n3;
        ay += bf2f((unsigned short)(u0 >> 16)) * n0 + bf2f((unsigned short)(u1 >> 16)) * n1
            + bf2f((unsigned short)(u2 >> 16)) * n2 + bf2f((unsigned short)(u3 >> 16)) * n3;
    }
    for (int e = base + half; e < end; e += 2) {
        int s = edge_src[e];
        float n = norm_src[s];
        unsigned int u = h32[s * 32 + c2];
        ax += bf2f((unsigned short)u) * n;
        ay += bf2f((unsigned short)(u >> 16)) * n;
    }

    // combine the two halves (lane L and L^32 hold the same channel pair)
    ax += __shfl(ax, lane ^ 32, 64);
    ay += __shfl(ay, lane ^ 32, 64);

    if (half == 0) {
        unsigned int hu = h32[node * 32 + c2];
        float nd = norm_dst[node];
        float2 r;
        r.x = 0.8f * nd * ax + 0.2f * bf2f((unsigned short)hu);
        r.y = 0.8f * nd * ay + 0.2f * bf2f((unsigned short)(hu >> 16));
        *reinterpret_cast<float2*>(&out[node * C_OUT + c2 * 2]) = r;
    }
}

// ---------------------------------------------------------------------------
extern "C" void kernel_launch(void* const* d_in, const int* in_sizes, int n_in,
                              void* d_out, int out_size, void* d_ws, size_t ws_size,
                              hipStream_t stream) {
    const float* in_feat = (const float*)d_in[0];   // [N, 512]
    const float* W       = (const float*)d_in[1];   // [64, 512]
    const float* bias    = (const float*)d_in[2];   // [64]
    const int*   src     = (const int*)d_in[3];     // [E]
    const int*   dst     = (const int*)d_in[4];     // [E]
    float* out = (float*)d_out;                     // [N, 64]

    // workspace layout:
    //   h0b (N*64 bf16, 12.8MB) -- tmp (E u32, 12.8MB) aliases it exactly
    //   edge_src (E i32) | row_off (N+1) | norm_src (N) | norm_dst (N) |
    //   bc_dst(NB) | bc_src(NB) | base_d(NB+1) | base_s(NB+1) |
    //   cursor_d(NB) | cursor_s(NB) | tmp2 (E u8, 3.2MB)
    unsigned short* h0b = (unsigned short*)d_ws;
    unsigned int*   tmp = (unsigned int*)d_ws;                 // aliases h0b
    int*   edge_src = (int*)((char*)d_ws + (size_t)N_NODES * C_OUT * 2);
    int*   row_off  = edge_src + E_EDGES;
    float* norm_src = (float*)(row_off + N_NODES + 1);
    float* norm_dst = norm_src + N_NODES;
    int*   bc_dst   = (int*)(norm_dst + N_NODES);
    int*   bc_src   = bc_dst + NB;
    int*   base_d   = bc_src + NB;
    int*   base_s   = base_d + NB + 1;
    int*   cursor_d = base_s + NB + 1;
    int*   cursor_s = cursor_d + NB;
    unsigned char* tmp2 = (unsigned char*)(cursor_s + NB);

    zero_kernel<<<2, 256, 0, stream>>>(bc_dst, bc_src);
    p0_hist<<<NTILE, 256, 0, stream>>>(src, dst, bc_dst, bc_src);
    p1_scan<<<1, 512, 0, stream>>>(bc_dst, bc_src, base_d, cursor_d,
                                   base_s, cursor_s, row_off);
    p2_part<<<NTILE, 256, 0, stream>>>(src, dst, cursor_d, cursor_s, tmp, tmp2);
    p3_build<<<NB, 256, 0, stream>>>(tmp, tmp2, base_d, base_s, row_off,
                                     edge_src, norm_src, norm_dst);
    // gemm AFTER p3: h0b overwrites tmp's memory only once tmp is consumed
    gemm_kernel<<<(N_NODES + 63) / 64, 256, 0, stream>>>(in_feat, W, bias, h0b);
    gather_kernel<<<(N_NODES + 3) / 4, 256, 0, stream>>>(row_off, edge_src, h0b,
                                                         norm_src, norm_dst, out);
}

// Round 7
// 505.825 us; speedup vs baseline: 6.5284x; 1.0784x over previous
//
#include <hip/hip_runtime.h>

#define N_NODES 100000
#define E_EDGES 3200000
#define F_IN    512
#define C_OUT   64
#define NB      391      // coarse buckets: node >> 8 (256 nodes per bucket)
#define CAP     10240    // bucket capacity (mean 8184, sigma 90 -> 22 sigma)
#define TILE    16384    // edges per block in P2
#define NTILE   196      // ceil(E / TILE)

typedef __bf16 bf16x8 __attribute__((ext_vector_type(8)));
typedef float  f32x4  __attribute__((ext_vector_type(4)));
typedef float  f32x2  __attribute__((ext_vector_type(2)));

// fp32 -> bf16 (round-to-nearest-even), bit-level
static __device__ __forceinline__ unsigned short f2bf(float f) {
    unsigned int u = __float_as_uint(f);
    u = (u + 0x7FFFu + ((u >> 16) & 1u)) >> 16;
    return (unsigned short)u;
}
// bf16 bits -> fp32 (exact)
static __device__ __forceinline__ float bf2f(unsigned short b) {
    return __uint_as_float(((unsigned int)b) << 16);
}
// fp32 -> fp8 e4m3 (OCP on gfx950), single byte via HW convert
static __device__ __forceinline__ unsigned char f32_to_fp8(float v) {
    return (unsigned char)(__builtin_amdgcn_cvt_pk_fp8_f32(v, v, 0, false) & 0xFF);
}
// 2 packed fp8 -> 2 fp32 via HW convert (same HW format as encode)
static __device__ __forceinline__ f32x2 fp8x2_to_f32(unsigned short u) {
    return __builtin_amdgcn_cvt_pk_f32_fp8((int)(unsigned int)u, false);
}

// ---------------------------------------------------------------------------
// zero: bucket cursors only
// ---------------------------------------------------------------------------
__global__ __launch_bounds__(512) void zero_kernel(int* __restrict__ cursor_d,
                                                   int* __restrict__ cursor_s) {
    int idx = threadIdx.x;
    if (idx < NB) { cursor_d[idx] = 0; cursor_s[idx] = 0; }
}

// ---------------------------------------------------------------------------
// P2: two-pass dual partition into fixed-capacity bucket regions.
// Pass A: LDS histograms of dst>>8 / src>>8. Reserve: one global atomic per
// (block,bucket). Pass B: re-read (L2-hot) and write packed runs.
//   tmp [b*CAP..] : u32 (dst&255)<<24 | src      (dst-partitioned)
//   tmp2[b*CAP..] : u8  src&255                   (src-partitioned)
// ---------------------------------------------------------------------------
__global__ __launch_bounds__(512) void p2_part(const int* __restrict__ src,
                                               const int* __restrict__ dst,
                                               int* __restrict__ cursor_d,
                                               int* __restrict__ cursor_s,
                                               unsigned int* __restrict__ tmp,
                                               unsigned char* __restrict__ tmp2) {
    __shared__ int cd[NB];
    __shared__ int bd[NB];
    __shared__ int cs[NB];
    __shared__ int bs[NB];
    int t = threadIdx.x;
    for (int j = t; j < NB; j += 512) { cd[j] = 0; cs[j] = 0; }
    __syncthreads();
    int tb = blockIdx.x * TILE;
    // --- pass A: count ---
    #pragma unroll 4
    for (int i = 0; i < 32; ++i) {
        int e = tb + i * 512 + t;
        if (e < E_EDGES) {
            atomicAdd(&cd[dst[e] >> 8], 1);
            atomicAdd(&cs[src[e] >> 8], 1);
        }
    }
    __syncthreads();
    // --- reserve contiguous runs ---
    for (int j = t; j < NB; j += 512) {
        int c = cd[j];
        bd[j] = j * CAP + (c ? atomicAdd(&cursor_d[j], c) : 0);
        cd[j] = 0;
        c = cs[j];
        bs[j] = j * CAP + (c ? atomicAdd(&cursor_s[j], c) : 0);
        cs[j] = 0;
    }
    __syncthreads();
    // --- pass B: write ---
    #pragma unroll 4
    for (int i = 0; i < 32; ++i) {
        int e = tb + i * 512 + t;
        if (e < E_EDGES) {
            int s = src[e], d = dst[e];
            int db = d >> 8;
            int p = atomicAdd(&cd[db], 1);
            tmp[bd[db] + p] = ((unsigned int)(d & 255) << 24) | (unsigned int)s;
            int sb = s >> 8;
            int q = atomicAdd(&cs[sb], 1);
            tmp2[bs[sb] + q] = (unsigned char)(s & 255);
        }
    }
}

// ---------------------------------------------------------------------------
// P3: block b owns nodes [256b, 256b+256). Builds dst-CSR (row_beg/row_end,
// edge_src, norm_dst) and out-degree histogram from tmp2 -> norm_src.
// All heavy writes land inside one 40KB bucket region (L2-local).
// ---------------------------------------------------------------------------
__global__ __launch_bounds__(256) void p3_build(const unsigned int* __restrict__ tmp,
                                                const unsigned char* __restrict__ tmp2,
                                                const int* __restrict__ cursor_d,
                                                const int* __restrict__ cursor_s,
                                                int* __restrict__ row_beg,
                                                int* __restrict__ row_end,
                                                int* __restrict__ edge_src,
                                                float* __restrict__ norm_src,
                                                float* __restrict__ norm_dst) {
    __shared__ int cnt[256];
    __shared__ int off[256];
    __shared__ int lc[256];
    __shared__ int s[256];
    __shared__ int cnt2[256];
    int t = threadIdx.x;
    int b = blockIdx.x;
    int bbase = b * CAP;
    int bend  = bbase + cursor_d[b];
    int sbase = b * CAP;
    int send  = sbase + cursor_s[b];
    cnt[t] = 0;
    lc[t] = 0;
    cnt2[t] = 0;
    __syncthreads();
    for (int e = bbase + t; e < bend; e += 256)
        atomicAdd(&cnt[tmp[e] >> 24], 1);
    for (int e = sbase + t; e < send; e += 256)
        atomicAdd(&cnt2[tmp2[e]], 1);
    __syncthreads();
    int vv = cnt[t];
    s[t] = vv;
    __syncthreads();
    #pragma unroll
    for (int o = 1; o < 256; o <<= 1) {
        int add = (t >= o) ? s[t - o] : 0;
        __syncthreads();
        s[t] += add;
        __syncthreads();
    }
    off[t] = s[t] - vv;
    __syncthreads();
    int node = b * 256 + t;
    if (node < N_NODES) {
        row_beg[node] = bbase + off[t];
        row_end[node] = bbase + off[t] + vv;
        norm_dst[node] = rsqrtf((float)(vv < 1 ? 1 : vv));
        int dg = cnt2[t];
        norm_src[node] = rsqrtf((float)(dg < 1 ? 1 : dg));
    }
    for (int e = bbase + t; e < bend; e += 256) {
        unsigned int v = tmp[e];
        int dl = v >> 24;
        int p = atomicAdd(&lc[dl], 1);
        edge_src[bbase + off[dl] + p] = (int)(v & 0x00FFFFFFu);
    }
}

// ---------------------------------------------------------------------------
// GEMM (bf16 MFMA): writes h0b (bf16, for teleport term) AND
// h8[n][c] = fp8(h0[n][c] * norm_src[n])  (norm pre-folded for the gather).
// ---------------------------------------------------------------------------
__global__ __launch_bounds__(256) void gemm_kernel(const float* __restrict__ A,
                                                   const float* __restrict__ W,
                                                   const float* __restrict__ bias,
                                                   const float* __restrict__ norm_src,
                                                   unsigned short* __restrict__ h0b,
                                                   unsigned char* __restrict__ h8) {
    __shared__ unsigned short Wl[64 * 520];   // 66560 B

    const int tid  = threadIdx.x;
    const int w    = tid >> 6;
    const int lane = tid & 63;
    const int cl   = lane & 15;
    const int quad = lane >> 4;
    const int row0 = blockIdx.x * 64;

    #pragma unroll 8
    for (int j = 0; j < 32; ++j) {
        int e4 = (j * 256 + tid) * 4;
        float4 wv = *reinterpret_cast<const float4*>(&W[e4]);
        int c = e4 >> 9;
        int k = e4 & 511;
        unsigned short* d = &Wl[c * 520 + k];
        d[0] = f2bf(wv.x); d[1] = f2bf(wv.y); d[2] = f2bf(wv.z); d[3] = f2bf(wv.w);
    }
    __syncthreads();

    int arow = row0 + w * 16 + cl;
    if (arow >= N_NODES) arow = N_NODES - 1;
    const float* aptr = A + (size_t)arow * F_IN + quad * 8;

    f32x4 acc0 = {0.f, 0.f, 0.f, 0.f};
    f32x4 acc1 = {0.f, 0.f, 0.f, 0.f};
    f32x4 acc2 = {0.f, 0.f, 0.f, 0.f};
    f32x4 acc3 = {0.f, 0.f, 0.f, 0.f};

    for (int k0 = 0; k0 < F_IN; k0 += 32) {
        float4 p = *reinterpret_cast<const float4*>(aptr + k0);
        float4 q = *reinterpret_cast<const float4*>(aptr + k0 + 4);
        bf16x8 af;
        af[0] = (__bf16)p.x; af[1] = (__bf16)p.y; af[2] = (__bf16)p.z; af[3] = (__bf16)p.w;
        af[4] = (__bf16)q.x; af[5] = (__bf16)q.y; af[6] = (__bf16)q.z; af[7] = (__bf16)q.w;

        const unsigned short* wb = &Wl[k0 + quad * 8];
        bf16x8 b0 = *reinterpret_cast<const bf16x8*>(wb + (cl +  0) * 520);
        bf16x8 b1 = *reinterpret_cast<const bf16x8*>(wb + (cl + 16) * 520);
        bf16x8 b2 = *reinterpret_cast<const bf16x8*>(wb + (cl + 32) * 520);
        bf16x8 b3 = *reinterpret_cast<const bf16x8*>(wb + (cl + 48) * 520);

        acc0 = __builtin_amdgcn_mfma_f32_16x16x32_bf16(af, b0, acc0, 0, 0, 0);
        acc1 = __builtin_amdgcn_mfma_f32_16x16x32_bf16(af, b1, acc1, 0, 0, 0);
        acc2 = __builtin_amdgcn_mfma_f32_16x16x32_bf16(af, b2, acc2, 0, 0, 0);
        acc3 = __builtin_amdgcn_mfma_f32_16x16x32_bf16(af, b3, acc3, 0, 0, 0);
    }

    float bias0 = bias[cl +  0];
    float bias1 = bias[cl + 16];
    float bias2 = bias[cl + 32];
    float bias3 = bias[cl + 48];
    #pragma unroll
    for (int r = 0; r < 4; ++r) {
        int row = row0 + w * 16 + quad * 4 + r;
        if (row < N_NODES) {
            float v0 = acc0[r] + bias0;
            float v1 = acc1[r] + bias1;
            float v2 = acc2[r] + bias2;
            float v3 = acc3[r] + bias3;
            unsigned short* o = &h0b[(size_t)row * C_OUT + cl];
            o[ 0] = f2bf(v0);
            o[16] = f2bf(v1);
            o[32] = f2bf(v2);
            o[48] = f2bf(v3);
            float ns = norm_src[row];
            unsigned char* o8 = &h8[(size_t)row * C_OUT + cl];
            o8[ 0] = f32_to_fp8(v0 * ns);
            o8[16] = f32_to_fp8(v1 * ns);
            o8[32] = f32_to_fp8(v2 * ns);
            o8[48] = f32_to_fp8(v3 * ns);
        }
    }
}

// ---------------------------------------------------------------------------
// gather: one wave64 per dst node. 32 lanes x 2 channels; 2 edge slots
// (half = lane>>5); 8-deep unroll per slot = 16 edges in flight.
// h8 rows are fp8 with norm_src pre-folded: one 64B line per edge, pure adds.
// ---------------------------------------------------------------------------
__global__ __launch_bounds__(256) void gather_kernel(const int* __restrict__ row_beg,
                                                     const int* __restrict__ row_end,
                                                     const int* __restrict__ edge_src,
                                                     const unsigned char* __restrict__ h8,
                                                     const unsigned short* __restrict__ h0b,
                                                     const float* __restrict__ norm_dst,
                                                     float* __restrict__ out) {
    int node = blockIdx.x * 4 + (threadIdx.x >> 6);
    int lane = threadIdx.x & 63;
    if (node >= N_NODES) return;
    int half = lane >> 5;          // edge slot 0/1
    int c2   = lane & 31;          // channel pair 2*c2, 2*c2+1

    const unsigned short* h8p = reinterpret_cast<const unsigned short*>(h8); // row stride 32
    const unsigned int*   h32 = reinterpret_cast<const unsigned int*>(h0b);  // row stride 32

    int beg = row_beg[node];
    int end = row_end[node];
    float ax = 0.0f, ay = 0.0f;

    int base = beg;
    for (; base + 16 <= end; base += 16) {
        int e0 = base + half;
        int s0 = edge_src[e0 +  0];
        int s1 = edge_src[e0 +  2];
        int s2 = edge_src[e0 +  4];
        int s3 = edge_src[e0 +  6];
        int s4 = edge_src[e0 +  8];
        int s5 = edge_src[e0 + 10];
        int s6 = edge_src[e0 + 12];
        int s7 = edge_src[e0 + 14];
        unsigned short u0 = h8p[s0 * 32 + c2];
        unsigned short u1 = h8p[s1 * 32 + c2];
        unsigned short u2 = h8p[s2 * 32 + c2];
        unsigned short u3 = h8p[s3 * 32 + c2];
        unsigned short u4 = h8p[s4 * 32 + c2];
        unsigned short u5 = h8p[s5 * 32 + c2];
        unsigned short u6 = h8p[s6 * 32 + c2];
        unsigned short u7 = h8p[s7 * 32 + c2];
        f32x2 f0 = fp8x2_to_f32(u0);
        f32x2 f1 = fp8x2_to_f32(u1);
        f32x2 f2 = fp8x2_to_f32(u2);
        f32x2 f3 = fp8x2_to_f32(u3);
        f32x2 f4 = fp8x2_to_f32(u4);
        f32x2 f5 = fp8x2_to_f32(u5);
        f32x2 f6 = fp8x2_to_f32(u6);
        f32x2 f7 = fp8x2_to_f32(u7);
        ax += (f0[0] + f1[0]) + (f2[0] + f3[0]) + (f4[0] + f5[0]) + (f6[0] + f7[0]);
        ay += (f0[1] + f1[1]) + (f2[1] + f3[1]) + (f4[1] + f5[1]) + (f6[1] + f7[1]);
    }
    for (int e = base + half; e < end; e += 2) {
        int s = edge_src[e];
        f32x2 f = fp8x2_to_f32(h8p[s * 32 + c2]);
        ax += f[0];
        ay += f[1];
    }

    ax += __shfl(ax, lane ^ 32, 64);
    ay += __shfl(ay, lane ^ 32, 64);

    if (half == 0) {
        unsigned int hu = h32[node * 32 + c2];
        float nd = norm_dst[node];
        float2 r;
        r.x = 0.8f * nd * ax + 0.2f * bf2f((unsigned short)hu);
        r.y = 0.8f * nd * ay + 0.2f * bf2f((unsigned short)(hu >> 16));
        *reinterpret_cast<float2*>(&out[node * C_OUT + c2 * 2]) = r;
    }
}

// ---------------------------------------------------------------------------
extern "C" void kernel_launch(void* const* d_in, const int* in_sizes, int n_in,
                              void* d_out, int out_size, void* d_ws, size_t ws_size,
                              hipStream_t stream) {
    const float* in_feat = (const float*)d_in[0];   // [N, 512]
    const float* W       = (const float*)d_in[1];   // [64, 512]
    const float* bias    = (const float*)d_in[2];   // [64]
    const int*   src     = (const int*)d_in[3];     // [E]
    const int*   dst     = (const int*)d_in[4];     // [E]
    float* out = (float*)d_out;                     // [N, 64]

    // workspace layout (no aliasing; ws is ~800MB, we use ~57MB):
    char* p = (char*)d_ws;
    unsigned short* h0b = (unsigned short*)p;  p += (size_t)N_NODES * C_OUT * 2;   // 12.8MB
    unsigned char*  h8  = (unsigned char*)p;   p += (size_t)N_NODES * C_OUT;       // 6.4MB
    unsigned int*   tmp = (unsigned int*)p;    p += (size_t)NB * CAP * 4;          // 16MB
    unsigned char*  tmp2= (unsigned char*)p;   p += (size_t)NB * CAP;              // 4MB
    int*   edge_src = (int*)p;                 p += (size_t)NB * CAP * 4;          // 16MB
    int*   row_beg  = (int*)p;                 p += (size_t)N_NODES * 4;
    int*   row_end  = (int*)p;                 p += (size_t)N_NODES * 4;
    float* norm_src = (float*)p;               p += (size_t)N_NODES * 4;
    float* norm_dst = (float*)p;               p += (size_t)N_NODES * 4;
    int*   cursor_d = (int*)p;                 p += (size_t)NB * 4;
    int*   cursor_s = (int*)p;

    zero_kernel<<<1, 512, 0, stream>>>(cursor_d, cursor_s);
    p2_part<<<NTILE, 512, 0, stream>>>(src, dst, cursor_d, cursor_s, tmp, tmp2);
    p3_build<<<NB, 256, 0, stream>>>(tmp, tmp2, cursor_d, cursor_s, row_beg,
                                     row_end, edge_src, norm_src, norm_dst);
    gemm_kernel<<<(N_NODES + 63) / 64, 256, 0, stream>>>(in_feat, W, bias,
                                                         norm_src, h0b, h8);
    gather_kernel<<<(N_NODES + 3) / 4, 256, 0, stream>>>(row_beg, row_end,
                                                         edge_src, h8, h0b,
                                                         norm_dst, out);
}